// Round 1
// baseline (1301.371 us; speedup 1.0000x reference)
//
#include <hip/hip_runtime.h>
#include <hip/hip_bf16.h>

// HunyuanTopKGate: x[4096,4096] fp32, wg[64,4096] fp32 ->
//   combine_weights [T,E,C] fp32 ++ dispatch_mask [T,E,C] (as fp32 0/1)
// C = out_size/(2*T*E) = 2268 -> 4.76 GB output zero-fill (~765us at the
// 6.2 TB/s fill ceiling) is the roofline pole.
//
// Round 11: the prior pipeline was SERIAL: memset(4.76GB, ~765us) then
// gemm (~300us) then tail. Fill is store-BW-bound (needs ~10 B/cy/CU),
// gemm is VALU/MFMA/LDS-bound (reads only 64MB) -- disjoint pipes.
// Fuse: each gemm thread streams its slice of the zero-fill as
// nontemporal dwordx4 stores interleaved into the K-loop (~284 stores
// per s-step). The per-step __syncthreads drains vmcnt, pacing each step
// at its store-drain rate, so the mega-kernel runs at the write ceiling
// with the GEMM hidden underneath. Barrier structure is UNCHANGED (same
// __syncthreads call sites, uniform trip counts) -> no hang risk.
// verify(tol 1e-3) -> gated repair = R9's PROVEN fp64 split-K gemm.
//
// ws: partial[8][4096][64] f64 (16MB) | idx_kt | w_kt | flag

#define TOK 4096
#define HID 4096
#define NE  64
#define NK  8

typedef __attribute__((ext_vector_type(8))) short short8;   // 8 bf16
typedef __attribute__((ext_vector_type(4))) float f32x4;

__device__ __forceinline__ short f2bf(float f) {
  __hip_bfloat16 h = __float2bfloat16(f);   // RNE
  return *reinterpret_cast<short*>(&h);
}
__device__ __forceinline__ float bf2f(short s) {
  unsigned u = ((unsigned)(unsigned short)s) << 16;
  return __uint_as_float(u);
}
__device__ __forceinline__ void cvt3(float f, short& s0, short& s1, short& s2) {
  s0 = f2bf(f);
  float r1 = f - bf2f(s0);
  s1 = f2bf(r1);
  float r2 = r1 - bf2f(s1);
  s2 = f2bf(r2);
}

// ---------------- 1. bf16x3 MFMA GEMM + fused NT zero-fill ----------------
// Grid (64 token-tiles, nsplit k-slabs), 256 thr = 4 waves.
// Block: 64 tokens x 64 experts x kchunk. Wave w: token rows w*16..+15,
// all 4 expert 16-col tiles. LDS: 3 bf16 planes for x and wg, row stride
// 72 shorts (144B = 9*16: b128 frag reads 16B-aligned, 2-way banks = free).
// Fill: thread (bid,tid) owns out4[bid*256+tid + k*nblk*256], k=0..~2267,
// issued in per-step chunks so store drain overlaps the whole K-loop.
__global__ __launch_bounds__(256) void gemm_fill(
    const float* __restrict__ x, const float* __restrict__ wg,
    double* __restrict__ partial, int kchunk, int* __restrict__ flag,
    float* __restrict__ out, int out_n) {
  __shared__ __align__(16) short XA[3][64][72];   // 27.6 KB
  __shared__ __align__(16) short WB[3][64][72];   // 27.6 KB
  const int tid = threadIdx.x;
  if (blockIdx.x == 0 && blockIdx.y == 0 && tid == 0) *flag = 0;
  const int t0   = blockIdx.x * 64;
  const int k0   = blockIdx.y * kchunk;
  const int lane = tid & 63;
  const int w    = tid >> 6;
  const int m    = lane & 15;       // frag row/col within 16
  const int q    = lane >> 4;       // quad
  const int lrow = tid >> 2;        // staging: 4 threads per row
  const int lq   = tid & 3;         // 16 floats each

  // ---- fill bookkeeping (uniform across block except fi) ----
  const int    nblk    = gridDim.x * gridDim.y;            // 64*nsplit
  const int    bid     = blockIdx.y * gridDim.x + blockIdx.x;
  const size_t n4      = ((size_t)(unsigned)out_n) >> 2;   // float4 count
  const size_t fstride = (size_t)nblk * 256;
  size_t       fi      = (size_t)bid * 256 + tid;
  const int    steps   = kchunk >> 6;                      // K-loop trips
  const size_t titers  = (n4 + fstride - 1) / fstride;     // ~2268
  const size_t chunk   = (titers + (size_t)steps - 1) / (size_t)steps;
  f32x4* o4 = (f32x4*)out;
  const f32x4 z4 = (f32x4){0.f, 0.f, 0.f, 0.f};

  f32x4 acc[4];
#pragma unroll
  for (int nt = 0; nt < 4; ++nt) acc[nt] = (f32x4){0.f, 0.f, 0.f, 0.f};

  for (int s = 0; s < kchunk; s += 64) {
    const int kk = k0 + s;
#pragma unroll
    for (int c = 0; c < 4; ++c) {
      const int col = lq * 16 + c * 4;
      float4 xv = *(const float4*)&x [(size_t)(t0 + lrow) * HID + kk + col];
      float4 wv = *(const float4*)&wg[(size_t)lrow * HID + kk + col];
      short4 p0, p1, p2;
      cvt3(xv.x, p0.x, p1.x, p2.x);  cvt3(xv.y, p0.y, p1.y, p2.y);
      cvt3(xv.z, p0.z, p1.z, p2.z);  cvt3(xv.w, p0.w, p1.w, p2.w);
      *(short4*)&XA[0][lrow][col] = p0;
      *(short4*)&XA[1][lrow][col] = p1;
      *(short4*)&XA[2][lrow][col] = p2;
      cvt3(wv.x, p0.x, p1.x, p2.x);  cvt3(wv.y, p0.y, p1.y, p2.y);
      cvt3(wv.z, p0.z, p1.z, p2.z);  cvt3(wv.w, p0.w, p1.w, p2.w);
      *(short4*)&WB[0][lrow][col] = p0;
      *(short4*)&WB[1][lrow][col] = p1;
      *(short4*)&WB[2][lrow][col] = p2;
    }
    __syncthreads();
#pragma unroll
    for (int kc = 0; kc < 64; kc += 32) {
      short8 a0 = *(const short8*)&XA[0][w * 16 + m][kc + q * 8];
      short8 a1 = *(const short8*)&XA[1][w * 16 + m][kc + q * 8];
      short8 a2 = *(const short8*)&XA[2][w * 16 + m][kc + q * 8];
#pragma unroll
      for (int nt = 0; nt < 4; ++nt) {
        short8 b0 = *(const short8*)&WB[0][nt * 16 + m][kc + q * 8];
        short8 b1 = *(const short8*)&WB[1][nt * 16 + m][kc + q * 8];
        short8 b2 = *(const short8*)&WB[2][nt * 16 + m][kc + q * 8];
        acc[nt] = __builtin_amdgcn_mfma_f32_16x16x32_bf16(a0, b0, acc[nt], 0, 0, 0);
        acc[nt] = __builtin_amdgcn_mfma_f32_16x16x32_bf16(a0, b1, acc[nt], 0, 0, 0);
        acc[nt] = __builtin_amdgcn_mfma_f32_16x16x32_bf16(a1, b0, acc[nt], 0, 0, 0);
        acc[nt] = __builtin_amdgcn_mfma_f32_16x16x32_bf16(a0, b2, acc[nt], 0, 0, 0);
        acc[nt] = __builtin_amdgcn_mfma_f32_16x16x32_bf16(a1, b1, acc[nt], 0, 0, 0);
        acc[nt] = __builtin_amdgcn_mfma_f32_16x16x32_bf16(a2, b0, acc[nt], 0, 0, 0);
      }
    }
    // ---- interleaved zero-fill chunk (fire-and-forget NT stores) ----
    for (size_t c = 0; c < chunk && fi < n4; ++c, fi += fstride)
      __builtin_nontemporal_store(z4, o4 + fi);
    __syncthreads();
  }

  // leftover fill (rounding remainder) + scalar tail
  for (; fi < n4; fi += fstride)
    __builtin_nontemporal_store(z4, o4 + fi);
  if (bid == 0 && tid == 0)
    for (size_t i2 = n4 << 2; i2 < (size_t)(unsigned)out_n; ++i2) out[i2] = 0.f;

  // C/D: row = q*4 + v (token), col = m (expert within n-tile)  [m89/m91]
  double* base = partial + (size_t)blockIdx.y * TOK * NE;
#pragma unroll
  for (int nt = 0; nt < 4; ++nt)
#pragma unroll
    for (int v = 0; v < 4; ++v)
      base[(size_t)(t0 + w * 16 + q * 4 + v) * NE + nt * 16 + m] =
          (double)acc[nt][v];
}

// ---------------- 1b. verify: sample 512 logits vs exact fp64 dots --------
// tol 1e-3: passes bf16x3 noise (~1e-5 max), catches layout bugs (O(0.1+)).
__global__ __launch_bounds__(256) void verify_kernel(
    const float* __restrict__ x, const float* __restrict__ wg,
    const double* __restrict__ partial, int nsplit, int* __restrict__ flag) {
  const int gid  = blockIdx.x * blockDim.x + threadIdx.x;
  const int wid  = gid >> 6;          // 0..511
  const int lane = gid & 63;
  const int t = (wid * 521) & (TOK - 1);
  const int e = wid & 63;
  double acc = 0.0;
  for (int k = lane; k < HID; k += 64)
    acc = fma((double)x[(size_t)t * HID + k], (double)wg[(size_t)e * HID + k], acc);
#pragma unroll
  for (int off = 32; off; off >>= 1) acc += __shfl_xor(acc, off);
  if (lane == 0) {
    double got = 0.0;
    for (int p = 0; p < nsplit; ++p)
      got += partial[(size_t)p * TOK * NE + (size_t)t * NE + e];
    if (!(fabs(got - acc) <= 1e-3)) atomicOr(flag, 1);  // NaN-safe
  }
}

// ---------------- 1c. repair: R9's proven fp64 split-K gemm, flag-gated ---
__global__ __launch_bounds__(256) void repair_splitk(
    const float* __restrict__ x, const float* __restrict__ wg,
    double* __restrict__ partial, int kchunk, const int* __restrict__ flag) {
  if (*(volatile const int*)flag == 0) return;
  __shared__ float xs[16][68];
  __shared__ float wsh[64][68];
  const int tid = threadIdx.x;
  const int t0  = blockIdx.x * 16;
  const int k0  = blockIdx.y * kchunk;
  const int tok = tid & 15;
  const int eg  = tid >> 4;
  const int lrow = tid >> 4;
  const int lq   = tid & 15;
  double acc[4] = {0.0, 0.0, 0.0, 0.0};

  for (int s = 0; s < kchunk; s += 64) {
    const int kk = k0 + s;
    {
      float4 v = *(const float4*)&x[(size_t)(t0 + lrow) * HID + kk + lq * 4];
      *(float4*)&xs[lrow][lq * 4] = v;
    }
#pragma unroll
    for (int it = 0; it < 4; ++it) {
      int r = it * 16 + lrow;
      float4 v = *(const float4*)&wg[(size_t)r * HID + kk + lq * 4];
      *(float4*)&wsh[r][lq * 4] = v;
    }
    __syncthreads();
#pragma unroll
    for (int kc = 0; kc < 64; kc += 4) {
      float4 xv = *(const float4*)&xs[tok][kc];
#pragma unroll
      for (int j = 0; j < 4; ++j) {
        float4 wv = *(const float4*)&wsh[eg * 4 + j][kc];
        acc[j] = fma((double)xv.x, (double)wv.x, acc[j]);
        acc[j] = fma((double)xv.y, (double)wv.y, acc[j]);
        acc[j] = fma((double)xv.z, (double)wv.z, acc[j]);
        acc[j] = fma((double)xv.w, (double)wv.w, acc[j]);
      }
    }
    __syncthreads();
  }
  double* base = partial + (size_t)blockIdx.y * TOK * NE;
#pragma unroll
  for (int j = 0; j < 4; ++j)
    base[(size_t)(t0 + tok) * NE + eg * 4 + j] = acc[j];
}

// ---------------- 2. softmax + top-8 per token (one wave64/token) ----------
__global__ __launch_bounds__(256) void topk_kernel(
    const double* __restrict__ partial, int nsplit,
    int* __restrict__ idx_kt, float* __restrict__ w_kt) {
  const int gid  = blockIdx.x * blockDim.x + threadIdx.x;
  const int t    = gid >> 6;
  const int lane = gid & 63;

  double v = 0.0;
  for (int p = 0; p < nsplit; ++p)
    v += partial[(size_t)p * TOK * NE + (size_t)t * NE + lane];

  double m = v;
#pragma unroll
  for (int off = 32; off; off >>= 1) {
    double o = __shfl_xor(m, off);
    m = o > m ? o : m;
  }
  double g = exp(v - m);
  double s = g;
#pragma unroll
  for (int off = 32; off; off >>= 1) s += __shfl_xor(s, off);
  double gate = g / s;

  float key = (float)gate;    // fp32-rounded key, tie -> lower index
  double ssel = 0.0;
  int my_k = -1;
#pragma unroll
  for (int k = 0; k < NK; ++k) {
    float bv = key;
    int   bi = lane;
#pragma unroll
    for (int off = 32; off; off >>= 1) {
      float ov = __shfl_xor(bv, off);
      int   oi = __shfl_xor(bi, off);
      if (ov > bv || (ov == bv && oi < bi)) { bv = ov; bi = oi; }
    }
    ssel += __shfl(gate, bi);
    if (lane == bi) { my_k = k; key = -1.0f; }
  }
  double gs = ssel;
  const double eps = (double)1.1920929e-07f;
  if (gs < eps) gs = eps;

  if (my_k >= 0) {
    idx_kt[my_k * TOK + t] = lane;
    w_kt [my_k * TOK + t] = (float)(gate / gs);
  }
}

// ---------------- 3. fused rank + scatter ------------------------------
__global__ __launch_bounds__(1024) void rank_scatter(
    const int* __restrict__ idx_kt, const float* __restrict__ w_kt,
    float* __restrict__ out, int C) {
  const int e    = blockIdx.x;
  const int tid  = threadIdx.x;
  const int lane = tid & 63;
  const int w    = tid >> 6;          // 0..15
  __shared__ int wt[16];
  int running = 0;
  const unsigned long long below = (1ull << lane) - 1ull;

  for (int i0 = 0; i0 < NK * TOK; i0 += 1024) {
    const int i = i0 + tid;
    const bool mhit = (idx_kt[i] == e);
    unsigned long long mask = __ballot(mhit);
    if (lane == 0) wt[w] = __popcll(mask);
    __syncthreads();
    int woff = 0, tot = 0;
#pragma unroll
    for (int j = 0; j < 16; ++j) {
      int c = wt[j];
      tot += c;
      if (j < w) woff += c;
    }
    if (mhit) {
      const int c = running + woff + __popcll(mask & below);
      if (c < C) {
        const int t = i & (TOK - 1);
        size_t off = ((size_t)t * NE + e) * (size_t)C + (size_t)c;
        out[off] = w_kt[i];                          // combine_weights
        out[(size_t)TOK * NE * C + off] = 1.0f;      // dispatch_mask
      }
    }
    running += tot;
    __syncthreads();
  }
}

extern "C" void kernel_launch(void* const* d_in, const int* in_sizes, int n_in,
                              void* d_out, int out_size, void* d_ws, size_t ws_size,
                              hipStream_t stream) {
  const float* x  = (const float*)d_in[0];   // [4096,4096]
  const float* wg = (const float*)d_in[1];   // [64,4096]
  float* out = (float*)d_out;

  const int C = out_size / (2 * TOK * NE);   // capacity from output size

  const size_t slab = (size_t)TOK * NE * sizeof(double);   // 2 MB per partial
  const size_t tail = 2 * (size_t)NK * TOK * sizeof(int);  // idx + w
  int nsplit = 8;
  while (nsplit > 1 && (size_t)nsplit * slab + tail + 64 > ws_size) nsplit >>= 1;
  const int kchunk = HID / nsplit;

  char* ws = (char*)d_ws;
  double* partial = (double*)ws;
  int*    idx_kt  = (int*)  (ws + (size_t)nsplit * slab);
  float*  w_kt    = (float*)(ws + (size_t)nsplit * slab + (size_t)NK * TOK * 4);
  int*    flag    = (int*)  (ws + (size_t)nsplit * slab + tail);

  // zero-fill of the 4.76 GB output is FUSED into gemm_fill (NT stores
  // interleaved with the K-loop) -- no separate memset dispatch.

  dim3 bgrid(TOK / 64, nsplit);   // 64 x 8 = 512 blocks
  dim3 rgrid(TOK / 16, nsplit);   // repair: 256 x 8
  gemm_fill    <<<bgrid, 256, 0, stream>>>(x, wg, partial, kchunk, flag, out, out_size);
  verify_kernel<<<128, 256, 0, stream>>>(x, wg, partial, nsplit, flag);
  repair_splitk<<<rgrid, 256, 0, stream>>>(x, wg, partial, kchunk, flag);
  topk_kernel  <<<TOK * 64 / 256, 256, 0, stream>>>(partial, nsplit, idx_kt, w_kt);
  rank_scatter <<<NE, 1024, 0, stream>>>(idx_kt, w_kt, out, C);
}

// Round 2
// 1289.644 us; speedup vs baseline: 1.0091x; 1.0091x over previous
//
#include <hip/hip_runtime.h>
#include <hip/hip_bf16.h>

// HunyuanTopKGate: x[4096,4096] fp32, wg[64,4096] fp32 ->
//   combine_weights [T,E,C] fp32 ++ dispatch_mask [T,E,C] (as fp32 0/1)
// C = out_size/(2*T*E) = 2268 -> 4.76 GB output zero-fill (~755us at the
// 6.3 TB/s fill ceiling) is the roofline pole.
//
// Round 12: R11 post-mortem: interleaving NT fill stores INSIDE the
// gemm's barriered K-loop (a) tripped verify -> fp64 repair (~500us) ran
// every iter, (b) per-step vmcnt(0) drains made the write stream bursty.
// Fix: block-level specialization in ONE dispatch. Blocks [0,ngemm) =
// R10's verified bf16x3 MFMA gemm (structure unchanged); blocks
// [ngemm,+1536) = barrier-free grid-stride NT zero-fill. To co-reside,
// gemm LDS is halved to 27.6KB by moving wg's bf16x3 planes to a 1.5MB
// ws buffer (prep_wg prepass, identical cvt3 -> bit-identical B values);
// gemm loads B-frags straight from global (L2-resident). launch_bounds
// (256,3) -> 3 blocks/CU: 2 gemm + 1+ fill per CU; fill saturates write
// BW (memset does 6.3TB/s at 3.4 waves/CU) while gemm hides underneath.
// verify(tol 1e-3) -> gated repair = R9's PROVEN fp64 split-K gemm.
//
// ws: partial[nsplit][4096][64] f64 | idx_kt | w_kt | flag | wp[3][64][4096] bf16

#define TOK 4096
#define HID 4096
#define NE  64
#define NK  8

typedef __attribute__((ext_vector_type(8))) short short8;   // 8 bf16
typedef __attribute__((ext_vector_type(4))) float f32x4;

__device__ __forceinline__ short f2bf(float f) {
  __hip_bfloat16 h = __float2bfloat16(f);   // RNE
  return *reinterpret_cast<short*>(&h);
}
__device__ __forceinline__ float bf2f(short s) {
  unsigned u = ((unsigned)(unsigned short)s) << 16;
  return __uint_as_float(u);
}
__device__ __forceinline__ void cvt3(float f, short& s0, short& s1, short& s2) {
  s0 = f2bf(f);
  float r1 = f - bf2f(s0);
  s1 = f2bf(r1);
  float r2 = r1 - bf2f(s1);
  s2 = f2bf(r2);
}

// ---------------- 0. prep: wg fp32 -> 3 bf16 planes in ws -----------------
// wp layout: [3][64][4096] bf16 (plane-major). 64x4096 = 65536 float4s,
// 256 blocks x 256 thr = one float4/thread. ~5us.
__global__ __launch_bounds__(256) void prep_wg(
    const float* __restrict__ wg, short* __restrict__ wp) {
  const int idx = blockIdx.x * 256 + threadIdx.x;   // 0..65535
  const int e  = idx >> 10;                         // row (1024 f4/row)
  const int kq = idx & 1023;
  float4 v = *(const float4*)&wg[(size_t)e * HID + kq * 4];
  short4 p0, p1, p2;
  cvt3(v.x, p0.x, p1.x, p2.x);  cvt3(v.y, p0.y, p1.y, p2.y);
  cvt3(v.z, p0.z, p1.z, p2.z);  cvt3(v.w, p0.w, p1.w, p2.w);
  *(short4*)&wp[((size_t)  0 + e) * HID + kq * 4] = p0;
  *(short4*)&wp[((size_t) 64 + e) * HID + kq * 4] = p1;
  *(short4*)&wp[((size_t)128 + e) * HID + kq * 4] = p2;
}

// ---------------- 1. mega: bf16x3 MFMA gemm blocks + NT fill blocks -------
// gemm blocks (bx < ngemm): tile = bx&63 (64 tokens), slab = bx>>6.
// 4 waves; wave w: token rows w*16..+15, all 4 expert 16-col tiles.
// A staged via LDS (x unique per block), stride 72 shorts (16B-aligned
// b128 frags, 2-way banks = free). B-frags read direct from wp (1.5MB,
// L2-resident; 16B-aligned: kk+kc+q*8 is a multiple of 8 shorts).
// fill blocks (bx >= ngemm): grid-stride NT dwordx4 zero-stores, no LDS
// use, no barriers -> self-pacing write stream.
__global__ __launch_bounds__(256, 3) void mega(
    const float* __restrict__ x, const short* __restrict__ wp,
    double* __restrict__ partial, int kchunk, int ngemm, int nfill,
    int* __restrict__ flag, float* __restrict__ out, int out_n) {
  const int bx  = blockIdx.x;
  const int tid = threadIdx.x;

  if (bx >= ngemm) {                    // ---- fill branch ----
    const int    fid    = bx - ngemm;
    const size_t n4     = ((size_t)(unsigned)out_n) >> 2;
    const size_t stride = (size_t)nfill * 256;
    f32x4* o4 = (f32x4*)out;
    const f32x4 z4 = (f32x4){0.f, 0.f, 0.f, 0.f};
    for (size_t i = (size_t)fid * 256 + tid; i < n4; i += stride)
      __builtin_nontemporal_store(z4, o4 + i);
    if (fid == 0 && tid == 0)           // out_n % 4 == 0 -> empty, kept safe
      for (size_t i2 = n4 << 2; i2 < (size_t)(unsigned)out_n; ++i2) out[i2] = 0.f;
    return;
  }

  // ---- gemm branch (R10 structure, WB-LDS removed) ----
  __shared__ __align__(16) short XA[3][64][72];   // 27.6 KB
  if (bx == 0 && tid == 0) *flag = 0;
  const int tileid = bx & 63;
  const int slab   = bx >> 6;
  const int t0   = tileid * 64;
  const int k0   = slab * kchunk;
  const int lane = tid & 63;
  const int w    = tid >> 6;
  const int m    = lane & 15;       // frag row/col within 16
  const int q    = lane >> 4;       // quad
  const int lrow = tid >> 2;        // staging: 4 threads per row
  const int lq   = tid & 3;         // 16 floats each

  f32x4 acc[4];
#pragma unroll
  for (int nt = 0; nt < 4; ++nt) acc[nt] = (f32x4){0.f, 0.f, 0.f, 0.f};

  for (int s = 0; s < kchunk; s += 64) {
    const int kk = k0 + s;
#pragma unroll
    for (int c = 0; c < 4; ++c) {
      const int col = lq * 16 + c * 4;
      float4 xv = *(const float4*)&x[(size_t)(t0 + lrow) * HID + kk + col];
      short4 p0, p1, p2;
      cvt3(xv.x, p0.x, p1.x, p2.x);  cvt3(xv.y, p0.y, p1.y, p2.y);
      cvt3(xv.z, p0.z, p1.z, p2.z);  cvt3(xv.w, p0.w, p1.w, p2.w);
      *(short4*)&XA[0][lrow][col] = p0;
      *(short4*)&XA[1][lrow][col] = p1;
      *(short4*)&XA[2][lrow][col] = p2;
    }
    __syncthreads();
#pragma unroll
    for (int kc = 0; kc < 64; kc += 32) {
      short8 a0 = *(const short8*)&XA[0][w * 16 + m][kc + q * 8];
      short8 a1 = *(const short8*)&XA[1][w * 16 + m][kc + q * 8];
      short8 a2 = *(const short8*)&XA[2][w * 16 + m][kc + q * 8];
#pragma unroll
      for (int nt = 0; nt < 4; ++nt) {
        const size_t roff = (size_t)(nt * 16 + m) * HID + (kk + kc + q * 8);
        short8 b0 = *(const short8*)&wp[roff];                       // plane 0
        short8 b1 = *(const short8*)&wp[(size_t) 64 * HID + roff];   // plane 1
        short8 b2 = *(const short8*)&wp[(size_t)128 * HID + roff];   // plane 2
        acc[nt] = __builtin_amdgcn_mfma_f32_16x16x32_bf16(a0, b0, acc[nt], 0, 0, 0);
        acc[nt] = __builtin_amdgcn_mfma_f32_16x16x32_bf16(a0, b1, acc[nt], 0, 0, 0);
        acc[nt] = __builtin_amdgcn_mfma_f32_16x16x32_bf16(a1, b0, acc[nt], 0, 0, 0);
        acc[nt] = __builtin_amdgcn_mfma_f32_16x16x32_bf16(a0, b2, acc[nt], 0, 0, 0);
        acc[nt] = __builtin_amdgcn_mfma_f32_16x16x32_bf16(a1, b1, acc[nt], 0, 0, 0);
        acc[nt] = __builtin_amdgcn_mfma_f32_16x16x32_bf16(a2, b0, acc[nt], 0, 0, 0);
      }
    }
    __syncthreads();
  }

  // C/D: row = q*4 + v (token), col = m (expert within n-tile)  [m89/m91]
  double* base = partial + (size_t)slab * TOK * NE;
#pragma unroll
  for (int nt = 0; nt < 4; ++nt)
#pragma unroll
    for (int v = 0; v < 4; ++v)
      base[(size_t)(t0 + w * 16 + q * 4 + v) * NE + nt * 16 + m] =
          (double)acc[nt][v];
}

// ---------------- 1b. verify: sample 512 logits vs exact fp64 dots --------
// tol 1e-3: passes bf16x3 noise (~1e-5 max), catches layout bugs (O(0.1+)).
__global__ __launch_bounds__(256) void verify_kernel(
    const float* __restrict__ x, const float* __restrict__ wg,
    const double* __restrict__ partial, int nsplit, int* __restrict__ flag) {
  const int gid  = blockIdx.x * blockDim.x + threadIdx.x;
  const int wid  = gid >> 6;          // 0..511
  const int lane = gid & 63;
  const int t = (wid * 521) & (TOK - 1);
  const int e = wid & 63;
  double acc = 0.0;
  for (int k = lane; k < HID; k += 64)
    acc = fma((double)x[(size_t)t * HID + k], (double)wg[(size_t)e * HID + k], acc);
#pragma unroll
  for (int off = 32; off; off >>= 1) acc += __shfl_xor(acc, off);
  if (lane == 0) {
    double got = 0.0;
    for (int p = 0; p < nsplit; ++p)
      got += partial[(size_t)p * TOK * NE + (size_t)t * NE + e];
    if (!(fabs(got - acc) <= 1e-3)) atomicOr(flag, 1);  // NaN-safe
  }
}

// ---------------- 1c. repair: R9's proven fp64 split-K gemm, flag-gated ---
__global__ __launch_bounds__(256) void repair_splitk(
    const float* __restrict__ x, const float* __restrict__ wg,
    double* __restrict__ partial, int kchunk, const int* __restrict__ flag) {
  if (*(volatile const int*)flag == 0) return;
  __shared__ float xs[16][68];
  __shared__ float wsh[64][68];
  const int tid = threadIdx.x;
  const int t0  = blockIdx.x * 16;
  const int k0  = blockIdx.y * kchunk;
  const int tok = tid & 15;
  const int eg  = tid >> 4;
  const int lrow = tid >> 4;
  const int lq   = tid & 15;
  double acc[4] = {0.0, 0.0, 0.0, 0.0};

  for (int s = 0; s < kchunk; s += 64) {
    const int kk = k0 + s;
    {
      float4 v = *(const float4*)&x[(size_t)(t0 + lrow) * HID + kk + lq * 4];
      *(float4*)&xs[lrow][lq * 4] = v;
    }
#pragma unroll
    for (int it = 0; it < 4; ++it) {
      int r = it * 16 + lrow;
      float4 v = *(const float4*)&wg[(size_t)r * HID + kk + lq * 4];
      *(float4*)&wsh[r][lq * 4] = v;
    }
    __syncthreads();
#pragma unroll
    for (int kc = 0; kc < 64; kc += 4) {
      float4 xv = *(const float4*)&xs[tok][kc];
#pragma unroll
      for (int j = 0; j < 4; ++j) {
        float4 wv = *(const float4*)&wsh[eg * 4 + j][kc];
        acc[j] = fma((double)xv.x, (double)wv.x, acc[j]);
        acc[j] = fma((double)xv.y, (double)wv.y, acc[j]);
        acc[j] = fma((double)xv.z, (double)wv.z, acc[j]);
        acc[j] = fma((double)xv.w, (double)wv.w, acc[j]);
      }
    }
    __syncthreads();
  }
  double* base = partial + (size_t)blockIdx.y * TOK * NE;
#pragma unroll
  for (int j = 0; j < 4; ++j)
    base[(size_t)(t0 + tok) * NE + eg * 4 + j] = acc[j];
}

// ---------------- 2. softmax + top-8 per token (one wave64/token) ----------
__global__ __launch_bounds__(256) void topk_kernel(
    const double* __restrict__ partial, int nsplit,
    int* __restrict__ idx_kt, float* __restrict__ w_kt) {
  const int gid  = blockIdx.x * blockDim.x + threadIdx.x;
  const int t    = gid >> 6;
  const int lane = gid & 63;

  double v = 0.0;
  for (int p = 0; p < nsplit; ++p)
    v += partial[(size_t)p * TOK * NE + (size_t)t * NE + lane];

  double m = v;
#pragma unroll
  for (int off = 32; off; off >>= 1) {
    double o = __shfl_xor(m, off);
    m = o > m ? o : m;
  }
  double g = exp(v - m);
  double s = g;
#pragma unroll
  for (int off = 32; off; off >>= 1) s += __shfl_xor(s, off);
  double gate = g / s;

  float key = (float)gate;    // fp32-rounded key, tie -> lower index
  double ssel = 0.0;
  int my_k = -1;
#pragma unroll
  for (int k = 0; k < NK; ++k) {
    float bv = key;
    int   bi = lane;
#pragma unroll
    for (int off = 32; off; off >>= 1) {
      float ov = __shfl_xor(bv, off);
      int   oi = __shfl_xor(bi, off);
      if (ov > bv || (ov == bv && oi < bi)) { bv = ov; bi = oi; }
    }
    ssel += __shfl(gate, bi);
    if (lane == bi) { my_k = k; key = -1.0f; }
  }
  double gs = ssel;
  const double eps = (double)1.1920929e-07f;
  if (gs < eps) gs = eps;

  if (my_k >= 0) {
    idx_kt[my_k * TOK + t] = lane;
    w_kt [my_k * TOK + t] = (float)(gate / gs);
  }
}

// ---------------- 3. fused rank + scatter ------------------------------
__global__ __launch_bounds__(1024) void rank_scatter(
    const int* __restrict__ idx_kt, const float* __restrict__ w_kt,
    float* __restrict__ out, int C) {
  const int e    = blockIdx.x;
  const int tid  = threadIdx.x;
  const int lane = tid & 63;
  const int w    = tid >> 6;          // 0..15
  __shared__ int wt[16];
  int running = 0;
  const unsigned long long below = (1ull << lane) - 1ull;

  for (int i0 = 0; i0 < NK * TOK; i0 += 1024) {
    const int i = i0 + tid;
    const bool mhit = (idx_kt[i] == e);
    unsigned long long mask = __ballot(mhit);
    if (lane == 0) wt[w] = __popcll(mask);
    __syncthreads();
    int woff = 0, tot = 0;
#pragma unroll
    for (int j = 0; j < 16; ++j) {
      int c = wt[j];
      tot += c;
      if (j < w) woff += c;
    }
    if (mhit) {
      const int c = running + woff + __popcll(mask & below);
      if (c < C) {
        const int t = i & (TOK - 1);
        size_t off = ((size_t)t * NE + e) * (size_t)C + (size_t)c;
        out[off] = w_kt[i];                          // combine_weights
        out[(size_t)TOK * NE * C + off] = 1.0f;      // dispatch_mask
      }
    }
    running += tot;
    __syncthreads();
  }
}

extern "C" void kernel_launch(void* const* d_in, const int* in_sizes, int n_in,
                              void* d_out, int out_size, void* d_ws, size_t ws_size,
                              hipStream_t stream) {
  const float* x  = (const float*)d_in[0];   // [4096,4096]
  const float* wg = (const float*)d_in[1];   // [64,4096]
  float* out = (float*)d_out;

  const int C = out_size / (2 * TOK * NE);   // capacity from output size

  const size_t slab = (size_t)TOK * NE * sizeof(double);   // 2 MB per partial
  const size_t tail = 2 * (size_t)NK * TOK * sizeof(int);  // idx + w
  const size_t wpb  = (size_t)3 * NE * HID * sizeof(short);// 1.5 MB bf16 planes
  int nsplit = 8;
  while (nsplit > 1 && (size_t)nsplit * slab + tail + 64 + wpb > ws_size) nsplit >>= 1;
  const int kchunk = HID / nsplit;

  char* ws = (char*)d_ws;
  double* partial = (double*)ws;
  int*    idx_kt  = (int*)  (ws + (size_t)nsplit * slab);
  float*  w_kt    = (float*)(ws + (size_t)nsplit * slab + (size_t)NK * TOK * 4);
  int*    flag    = (int*)  (ws + (size_t)nsplit * slab + tail);
  short*  wp      = (short*)(ws + (size_t)nsplit * slab + tail + 64);

  const int ngemm = 64 * nsplit;    // 512 gemm blocks at nsplit=8
  const int nfill = 1536;           // barrier-free NT zero-fill blocks

  prep_wg      <<<256, 256, 0, stream>>>(wg, wp);
  mega         <<<ngemm + nfill, 256, 0, stream>>>(x, wp, partial, kchunk,
                                                   ngemm, nfill, flag, out, out_size);
  verify_kernel<<<128, 256, 0, stream>>>(x, wg, partial, nsplit, flag);
  dim3 rgrid(TOK / 16, nsplit);
  repair_splitk<<<rgrid, 256, 0, stream>>>(x, wg, partial, kchunk, flag);
  topk_kernel  <<<TOK * 64 / 256, 256, 0, stream>>>(partial, nsplit, idx_kt, w_kt);
  rank_scatter <<<NE, 1024, 0, stream>>>(idx_kt, w_kt, out, C);
}

// Round 3
// 1257.587 us; speedup vs baseline: 1.0348x; 1.0255x over previous
//
#include <hip/hip_runtime.h>
#include <hip/hip_bf16.h>

// HunyuanTopKGate: x[4096,4096] fp32, wg[64,4096] fp32 ->
//   combine_weights [T,E,C] fp32 ++ dispatch_mask [T,E,C] (as fp32 0/1)
// C = out_size/(2*T*E) = 2268 -> 4.76 GB output zero-fill (~760us at the
// 6.2 TB/s fill ceiling) is the roofline pole.
//
// Round 13: THEORY SHIFT. R12's profile shows a 30.5ms fill writing
// 1.19GB at 39 GB/s = PCIe bandwidth -> d_ws is host-pinned, NOT HBM.
// That explains the whole session: partial[16MB] written to ws costs
// ~250us PCIe in the gemm epilogue + ~250us PCIe read in topk -- the
// "fp64 gemm is 500us regardless of occupancy" (R9) and "bf16x3 gemm is
// still 420us" (R10) were never compute-bound; they were ws round-trips.
// The bf16x3 gemm's real compute is ~12.9 GFLOP = tens of us.
// Fix: carve scratch (partial + flag, 17MB) from the TAIL of d_out
// (device HBM). Run gemm/verify/repair/topk against it, THEN memset the
// full output (erasing the dead scratch), then scatter. Only idx/w
// (256KB) stay in ws to survive the memset (~8us PCIe). All kernels are
// R10-verbatim; if the theory is wrong this is work-identical to R10's
// 1237us -> no regression possible.
//
// ws: idx_kt[8*4096] int | w_kt[8*4096] float   (256 KB only)
// d_out tail scratch (pre-memset only): partial[8][4096][64] f64 | flag

#define TOK 4096
#define HID 4096
#define NE  64
#define NK  8
#define NSPLIT 8

typedef __attribute__((ext_vector_type(8))) short short8;   // 8 bf16
typedef __attribute__((ext_vector_type(4))) float f32x4;

__device__ __forceinline__ short f2bf(float f) {
  __hip_bfloat16 h = __float2bfloat16(f);   // RNE
  return *reinterpret_cast<short*>(&h);
}
__device__ __forceinline__ float bf2f(short s) {
  unsigned u = ((unsigned)(unsigned short)s) << 16;
  return __uint_as_float(u);
}
__device__ __forceinline__ void cvt3(float f, short& s0, short& s1, short& s2) {
  s0 = f2bf(f);
  float r1 = f - bf2f(s0);
  s1 = f2bf(r1);
  float r2 = r1 - bf2f(s1);
  s2 = f2bf(r2);
}

// ---------------- 1. bf16x3 MFMA GEMM (R10 verbatim) ----------------
// Grid (64 token-tiles, 8 k-slabs), 256 thr = 4 waves.
// Block: 64 tokens x 64 experts x kchunk. Wave w: token rows w*16..+15,
// all 4 expert 16-col tiles. LDS: 3 bf16 planes for x and wg, row stride
// 72 shorts (144B: b128 frag reads 16B-aligned, 2-way banks = free).
__global__ __launch_bounds__(256) void gemm_bf16x3(
    const float* __restrict__ x, const float* __restrict__ wg,
    double* __restrict__ partial, int kchunk, int* __restrict__ flag) {
  __shared__ __align__(16) short XA[3][64][72];   // 27.6 KB
  __shared__ __align__(16) short WB[3][64][72];   // 27.6 KB
  const int tid = threadIdx.x;
  if (blockIdx.x == 0 && blockIdx.y == 0 && tid == 0) *flag = 0;
  const int t0   = blockIdx.x * 64;
  const int k0   = blockIdx.y * kchunk;
  const int lane = tid & 63;
  const int w    = tid >> 6;
  const int m    = lane & 15;       // frag row/col within 16
  const int q    = lane >> 4;       // quad
  const int lrow = tid >> 2;        // staging: 4 threads per row
  const int lq   = tid & 3;         // 16 floats each

  f32x4 acc[4];
#pragma unroll
  for (int nt = 0; nt < 4; ++nt) acc[nt] = (f32x4){0.f, 0.f, 0.f, 0.f};

  for (int s = 0; s < kchunk; s += 64) {
    const int kk = k0 + s;
#pragma unroll
    for (int c = 0; c < 4; ++c) {
      const int col = lq * 16 + c * 4;
      float4 xv = *(const float4*)&x [(size_t)(t0 + lrow) * HID + kk + col];
      float4 wv = *(const float4*)&wg[(size_t)lrow * HID + kk + col];
      short4 p0, p1, p2;
      cvt3(xv.x, p0.x, p1.x, p2.x);  cvt3(xv.y, p0.y, p1.y, p2.y);
      cvt3(xv.z, p0.z, p1.z, p2.z);  cvt3(xv.w, p0.w, p1.w, p2.w);
      *(short4*)&XA[0][lrow][col] = p0;
      *(short4*)&XA[1][lrow][col] = p1;
      *(short4*)&XA[2][lrow][col] = p2;
      cvt3(wv.x, p0.x, p1.x, p2.x);  cvt3(wv.y, p0.y, p1.y, p2.y);
      cvt3(wv.z, p0.z, p1.z, p2.z);  cvt3(wv.w, p0.w, p1.w, p2.w);
      *(short4*)&WB[0][lrow][col] = p0;
      *(short4*)&WB[1][lrow][col] = p1;
      *(short4*)&WB[2][lrow][col] = p2;
    }
    __syncthreads();
#pragma unroll
    for (int kc = 0; kc < 64; kc += 32) {
      short8 a0 = *(const short8*)&XA[0][w * 16 + m][kc + q * 8];
      short8 a1 = *(const short8*)&XA[1][w * 16 + m][kc + q * 8];
      short8 a2 = *(const short8*)&XA[2][w * 16 + m][kc + q * 8];
#pragma unroll
      for (int nt = 0; nt < 4; ++nt) {
        short8 b0 = *(const short8*)&WB[0][nt * 16 + m][kc + q * 8];
        short8 b1 = *(const short8*)&WB[1][nt * 16 + m][kc + q * 8];
        short8 b2 = *(const short8*)&WB[2][nt * 16 + m][kc + q * 8];
        acc[nt] = __builtin_amdgcn_mfma_f32_16x16x32_bf16(a0, b0, acc[nt], 0, 0, 0);
        acc[nt] = __builtin_amdgcn_mfma_f32_16x16x32_bf16(a0, b1, acc[nt], 0, 0, 0);
        acc[nt] = __builtin_amdgcn_mfma_f32_16x16x32_bf16(a1, b0, acc[nt], 0, 0, 0);
        acc[nt] = __builtin_amdgcn_mfma_f32_16x16x32_bf16(a0, b2, acc[nt], 0, 0, 0);
        acc[nt] = __builtin_amdgcn_mfma_f32_16x16x32_bf16(a1, b1, acc[nt], 0, 0, 0);
        acc[nt] = __builtin_amdgcn_mfma_f32_16x16x32_bf16(a2, b0, acc[nt], 0, 0, 0);
      }
    }
    __syncthreads();
  }

  // C/D: row = q*4 + v (token), col = m (expert within n-tile)  [m89/m91]
  double* base = partial + (size_t)blockIdx.y * TOK * NE;
#pragma unroll
  for (int nt = 0; nt < 4; ++nt)
#pragma unroll
    for (int v = 0; v < 4; ++v)
      base[(size_t)(t0 + w * 16 + q * 4 + v) * NE + nt * 16 + m] =
          (double)acc[nt][v];
}

// ---------------- 1b. verify: sample 512 logits vs exact fp64 dots --------
// tol 1e-3: passes bf16x3 noise (~1e-5 max), catches layout bugs (O(0.1+)).
__global__ __launch_bounds__(256) void verify_kernel(
    const float* __restrict__ x, const float* __restrict__ wg,
    const double* __restrict__ partial, int nsplit, int* __restrict__ flag) {
  const int gid  = blockIdx.x * blockDim.x + threadIdx.x;
  const int wid  = gid >> 6;          // 0..511
  const int lane = gid & 63;
  const int t = (wid * 521) & (TOK - 1);
  const int e = wid & 63;
  double acc = 0.0;
  for (int k = lane; k < HID; k += 64)
    acc = fma((double)x[(size_t)t * HID + k], (double)wg[(size_t)e * HID + k], acc);
#pragma unroll
  for (int off = 32; off; off >>= 1) acc += __shfl_xor(acc, off);
  if (lane == 0) {
    double got = 0.0;
    for (int p = 0; p < nsplit; ++p)
      got += partial[(size_t)p * TOK * NE + (size_t)t * NE + e];
    if (!(fabs(got - acc) <= 1e-3)) atomicOr(flag, 1);  // NaN-safe
  }
}

// ---------------- 1c. repair: R9's proven fp64 split-K gemm, flag-gated ---
__global__ __launch_bounds__(256) void repair_splitk(
    const float* __restrict__ x, const float* __restrict__ wg,
    double* __restrict__ partial, int kchunk, const int* __restrict__ flag) {
  if (*(volatile const int*)flag == 0) return;
  __shared__ float xs[16][68];
  __shared__ float wsh[64][68];
  const int tid = threadIdx.x;
  const int t0  = blockIdx.x * 16;
  const int k0  = blockIdx.y * kchunk;
  const int tok = tid & 15;
  const int eg  = tid >> 4;
  const int lrow = tid >> 4;
  const int lq   = tid & 15;
  double acc[4] = {0.0, 0.0, 0.0, 0.0};

  for (int s = 0; s < kchunk; s += 64) {
    const int kk = k0 + s;
    {
      float4 v = *(const float4*)&x[(size_t)(t0 + lrow) * HID + kk + lq * 4];
      *(float4*)&xs[lrow][lq * 4] = v;
    }
#pragma unroll
    for (int it = 0; it < 4; ++it) {
      int r = it * 16 + lrow;
      float4 v = *(const float4*)&wg[(size_t)r * HID + kk + lq * 4];
      *(float4*)&wsh[r][lq * 4] = v;
    }
    __syncthreads();
#pragma unroll
    for (int kc = 0; kc < 64; kc += 4) {
      float4 xv = *(const float4*)&xs[tok][kc];
#pragma unroll
      for (int j = 0; j < 4; ++j) {
        float4 wv = *(const float4*)&wsh[eg * 4 + j][kc];
        acc[j] = fma((double)xv.x, (double)wv.x, acc[j]);
        acc[j] = fma((double)xv.y, (double)wv.y, acc[j]);
        acc[j] = fma((double)xv.z, (double)wv.z, acc[j]);
        acc[j] = fma((double)xv.w, (double)wv.w, acc[j]);
      }
    }
    __syncthreads();
  }
  double* base = partial + (size_t)blockIdx.y * TOK * NE;
#pragma unroll
  for (int j = 0; j < 4; ++j)
    base[(size_t)(t0 + tok) * NE + eg * 4 + j] = acc[j];
}

// ---------------- 2. softmax + top-8 per token (one wave64/token) ----------
__global__ __launch_bounds__(256) void topk_kernel(
    const double* __restrict__ partial, int nsplit,
    int* __restrict__ idx_kt, float* __restrict__ w_kt) {
  const int gid  = blockIdx.x * blockDim.x + threadIdx.x;
  const int t    = gid >> 6;
  const int lane = gid & 63;

  double v = 0.0;
  for (int p = 0; p < nsplit; ++p)
    v += partial[(size_t)p * TOK * NE + (size_t)t * NE + lane];

  double m = v;
#pragma unroll
  for (int off = 32; off; off >>= 1) {
    double o = __shfl_xor(m, off);
    m = o > m ? o : m;
  }
  double g = exp(v - m);
  double s = g;
#pragma unroll
  for (int off = 32; off; off >>= 1) s += __shfl_xor(s, off);
  double gate = g / s;

  float key = (float)gate;    // fp32-rounded key, tie -> lower index
  double ssel = 0.0;
  int my_k = -1;
#pragma unroll
  for (int k = 0; k < NK; ++k) {
    float bv = key;
    int   bi = lane;
#pragma unroll
    for (int off = 32; off; off >>= 1) {
      float ov = __shfl_xor(bv, off);
      int   oi = __shfl_xor(bi, off);
      if (ov > bv || (ov == bv && oi < bi)) { bv = ov; bi = oi; }
    }
    ssel += __shfl(gate, bi);
    if (lane == bi) { my_k = k; key = -1.0f; }
  }
  double gs = ssel;
  const double eps = (double)1.1920929e-07f;
  if (gs < eps) gs = eps;

  if (my_k >= 0) {
    idx_kt[my_k * TOK + t] = lane;
    w_kt [my_k * TOK + t] = (float)(gate / gs);
  }
}

// ---------------- 3. fused rank + scatter ------------------------------
__global__ __launch_bounds__(1024) void rank_scatter(
    const int* __restrict__ idx_kt, const float* __restrict__ w_kt,
    float* __restrict__ out, int C) {
  const int e    = blockIdx.x;
  const int tid  = threadIdx.x;
  const int lane = tid & 63;
  const int w    = tid >> 6;          // 0..15
  __shared__ int wt[16];
  int running = 0;
  const unsigned long long below = (1ull << lane) - 1ull;

  for (int i0 = 0; i0 < NK * TOK; i0 += 1024) {
    const int i = i0 + tid;
    const bool mhit = (idx_kt[i] == e);
    unsigned long long mask = __ballot(mhit);
    if (lane == 0) wt[w] = __popcll(mask);
    __syncthreads();
    int woff = 0, tot = 0;
#pragma unroll
    for (int j = 0; j < 16; ++j) {
      int c = wt[j];
      tot += c;
      if (j < w) woff += c;
    }
    if (mhit) {
      const int c = running + woff + __popcll(mask & below);
      if (c < C) {
        const int t = i & (TOK - 1);
        size_t off = ((size_t)t * NE + e) * (size_t)C + (size_t)c;
        out[off] = w_kt[i];                          // combine_weights
        out[(size_t)TOK * NE * C + off] = 1.0f;      // dispatch_mask
      }
    }
    running += tot;
    __syncthreads();
  }
}

extern "C" void kernel_launch(void* const* d_in, const int* in_sizes, int n_in,
                              void* d_out, int out_size, void* d_ws, size_t ws_size,
                              hipStream_t stream) {
  const float* x  = (const float*)d_in[0];   // [4096,4096]
  const float* wg = (const float*)d_in[1];   // [64,4096]
  float* out = (float*)d_out;

  const int C = out_size / (2 * TOK * NE);   // capacity from output size

  // ---- scratch carved from the TAIL of d_out (device HBM) ----
  // partial[8][4096][64] f64 (16MB) + flag. Dead before the memset that
  // erases them. 1KB-aligned.
  const size_t out_bytes = (size_t)out_size * sizeof(float);      // 4.756 GB
  const size_t psz       = (size_t)NSPLIT * TOK * NE * sizeof(double);  // 16 MB
  const size_t soff      = (out_bytes - (psz + 1024)) & ~(size_t)1023;
  char* ob = (char*)d_out;
  double* partial = (double*)(ob + soff);
  int*    flag    = (int*)  (ob + soff + psz);

  // ---- ws holds only what must SURVIVE the memset (256 KB) ----
  int*    idx_kt  = (int*)  d_ws;
  float*  w_kt    = (float*)((char*)d_ws + (size_t)NK * TOK * sizeof(int));

  const int kchunk = HID / NSPLIT;           // 512

  dim3 bgrid(TOK / 64, NSPLIT);   // 64 x 8 = 512 blocks
  dim3 rgrid(TOK / 16, NSPLIT);   // repair: 256 x 8
  gemm_bf16x3  <<<bgrid, 256, 0, stream>>>(x, wg, partial, kchunk, flag);
  verify_kernel<<<128, 256, 0, stream>>>(x, wg, partial, NSPLIT, flag);
  repair_splitk<<<rgrid, 256, 0, stream>>>(x, wg, partial, kchunk, flag);
  topk_kernel  <<<TOK * 64 / 256, 256, 0, stream>>>(partial, NSPLIT, idx_kt, w_kt);

  // zero the 4.76 GB output (erases the now-dead tail scratch)
  hipMemsetAsync(d_out, 0, out_bytes, stream);

  rank_scatter <<<NE, 1024, 0, stream>>>(idx_kt, w_kt, out, C);
}